// Round 1
// baseline (205.234 us; speedup 1.0000x reference)
//
#include <hip/hip_runtime.h>
#include <hip/hip_bf16.h>
#include <cstddef>

// Problem constants
#define BB 131072
#define DD 64
#define NREL 32

// Sort phase decomposition
#define BLOCKS_AC 256
#define SPB (BB / BLOCKS_AC)   // 512 samples per block

// ---------------- Phase A: per-block histogram + global reserve ----------------
__global__ __launch_bounds__(256) void phaseA_hist(
    const int* __restrict__ rels, int* __restrict__ gcount,
    int* __restrict__ blockOff) {
  __shared__ int hist[NREL];
  const int t = threadIdx.x;
  if (t < NREL) hist[t] = 0;
  __syncthreads();
  const int base = blockIdx.x * SPB;
#pragma unroll
  for (int i = 0; i < SPB / 256; ++i) {
    const int s = base + t + i * 256;
    atomicAdd(&hist[rels[s]], 1);
  }
  __syncthreads();
  if (t < NREL) {
    blockOff[blockIdx.x * NREL + t] = atomicAdd(&gcount[t], hist[t]);
  }
}

// ---------------- Phase C: scatter into sorted permutation ----------------
__global__ __launch_bounds__(256) void phaseC_scatter(
    const int* __restrict__ rels, const int* __restrict__ gcount,
    const int* __restrict__ blockOff, int* __restrict__ perm) {
  __shared__ int binBase[NREL];
  __shared__ int cnt[NREL];
  __shared__ int tmp[NREL];
  const int t = threadIdx.x;
  if (t < NREL) {
    tmp[t] = gcount[t];
    cnt[t] = 0;
  }
  __syncthreads();
  if (t == 0) {
    int acc = 0;
#pragma unroll
    for (int i = 0; i < NREL; ++i) {
      binBase[i] = acc;
      acc += tmp[i];
    }
  }
  __syncthreads();
  const int base = blockIdx.x * SPB;
  const int* bo = blockOff + blockIdx.x * NREL;
#pragma unroll
  for (int i = 0; i < SPB / 256; ++i) {
    const int s = base + t + i * 256;
    const int rv = rels[s];
    const int rank = atomicAdd(&cnt[rv], 1);
    perm[binBase[rv] + bo[rv] + rank] = s;
  }
}

// ---------------- Phase D: bilinear compute, one sample per lane ----------------
__global__ __launch_bounds__(256) void bilinear_compute(
    const float* __restrict__ e1g, const float* __restrict__ e2g,
    const int* __restrict__ rels, const float* __restrict__ relE,
    const int* __restrict__ perm, float* __restrict__ out) {
  const int gid = blockIdx.x * 256 + threadIdx.x;
  const int b = perm[gid];
  int rr = rels[b];

  // e2 resident in VGPRs (64 regs), loaded as float4s (coalesced 256B/lane)
  const float4* p2 = (const float4*)(e2g + (size_t)b * DD);
  float e2[DD];
#pragma unroll
  for (int k = 0; k < DD / 4; ++k) {
    const float4 v = p2[k];
    e2[4 * k + 0] = v.x;
    e2[4 * k + 1] = v.y;
    e2[4 * k + 2] = v.z;
    e2[4 * k + 3] = v.w;
  }
  const float* __restrict__ p1 = e1g + (size_t)b * DD;

  float score = 0.0f;
  // Waterfall over distinct relations in this wave. After sorting, 2017/2048
  // waves are uniform (1 iteration); <=31 boundary waves take 2.
  for (;;) {
    const unsigned long long todo = __ballot(rr >= 0);
    if (todo == 0ull) break;
    const int leader = (int)__ffsll(todo) - 1;
    // readlane -> SGPR: makes the R base pointer provably wave-uniform so
    // the compiler emits s_load for the relation matrix (SMEM pipe, free
    // broadcast, no per-lane VMEM traffic).
    const int r0 = __builtin_amdgcn_readlane(rr, leader);
    if (rr == r0) {
      const float* __restrict__ R = relE + (size_t)r0 * (DD * DD);
      float sc = 0.0f;
#pragma unroll 4
      for (int d = 0; d < DD; ++d) {
        const float a = p1[d];  // L1-hot reload, avoids dynamic reg indexing
        float t0 = 0.f, t1 = 0.f, t2 = 0.f, t3 = 0.f;
#pragma unroll
        for (int e = 0; e < DD; e += 4) {
          t0 = fmaf(R[d * DD + e + 0], e2[e + 0], t0);
          t1 = fmaf(R[d * DD + e + 1], e2[e + 1], t1);
          t2 = fmaf(R[d * DD + e + 2], e2[e + 2], t2);
          t3 = fmaf(R[d * DD + e + 3], e2[e + 3], t3);
        }
        sc = fmaf(a, (t0 + t1) + (t2 + t3), sc);
      }
      score = sc;
      rr = -1;  // done; drop out of waterfall
    }
  }
  out[b] = score;
}

extern "C" void kernel_launch(void* const* d_in, const int* in_sizes, int n_in,
                              void* d_out, int out_size, void* d_ws, size_t ws_size,
                              hipStream_t stream) {
  const float* e1 = (const float*)d_in[0];
  const float* e2 = (const float*)d_in[1];
  const int* rels = (const int*)d_in[2];
  const float* relE = (const float*)d_in[3];
  float* out = (float*)d_out;

  // Workspace layout (ints): perm[B] | gcount[32] | blockOff[BLOCKS_AC*32]
  int* perm = (int*)d_ws;
  int* gcount = perm + BB;
  int* blockOff = gcount + NREL;

  hipMemsetAsync(gcount, 0, NREL * sizeof(int), stream);
  phaseA_hist<<<BLOCKS_AC, 256, 0, stream>>>(rels, gcount, blockOff);
  phaseC_scatter<<<BLOCKS_AC, 256, 0, stream>>>(rels, gcount, blockOff, perm);
  bilinear_compute<<<BB / 256, 256, 0, stream>>>(e1, e2, rels, relE, perm, out);
}

// Round 2
// 195.037 us; speedup vs baseline: 1.0523x; 1.0523x over previous
//
#include <hip/hip_runtime.h>
#include <hip/hip_bf16.h>
#include <cstddef>

// Problem constants
#define BB 131072
#define DD 64
#define NREL 32

// Sort phase decomposition
#define BLOCKS_AC 512
#define SPB (BB / BLOCKS_AC)   // 256 samples per block, 1 per thread
#define CHUNKS 8
#define BPC (BLOCKS_AC / CHUNKS)  // 64 blocks per scan chunk

// ---------------- Phase A: per-block histogram (no global atomics) ----------------
__global__ __launch_bounds__(256) void phaseA_hist(
    const int* __restrict__ rels, int* __restrict__ blockCnt) {
  __shared__ int hist[NREL];
  const int t = threadIdx.x;
  if (t < NREL) hist[t] = 0;
  __syncthreads();
  const int s = blockIdx.x * SPB + t;
  atomicAdd(&hist[rels[s]], 1);
  __syncthreads();
  if (t < NREL) blockCnt[blockIdx.x * NREL + t] = hist[t];
}

// ---------------- Phase B: two-level scan -> per-(block,rel) offsets + bin bases --
__global__ __launch_bounds__(256) void phaseB_scan(
    const int* __restrict__ blockCnt, int* __restrict__ blockOff,
    int* __restrict__ binBase) {
  __shared__ int partial[CHUNKS][NREL];
  __shared__ int chunkBase[CHUNKS][NREL];
  __shared__ int binB[NREL];
  const int t = threadIdx.x;
  const int c = t >> 5;   // chunk 0..7
  const int r = t & 31;   // relation
  const int b0 = c * BPC;
  int run = 0;
#pragma unroll 4
  for (int b = 0; b < BPC; ++b) run += blockCnt[(b0 + b) * NREL + r];
  partial[c][r] = run;
  __syncthreads();
  if (t < NREL) {
    int acc = 0;
#pragma unroll
    for (int i = 0; i < CHUNKS; ++i) { chunkBase[i][t] = acc; acc += partial[i][t]; }
  }
  __syncthreads();
  if (t == 0) {
    int acc = 0;
#pragma unroll
    for (int i = 0; i < NREL; ++i) {
      binB[i] = acc;
      acc += chunkBase[CHUNKS - 1][i] + partial[CHUNKS - 1][i];
    }
  }
  __syncthreads();
  if (t < NREL) binBase[t] = binB[t];
  int run2 = chunkBase[c][r];
#pragma unroll 4
  for (int b = 0; b < BPC; ++b) {
    blockOff[(b0 + b) * NREL + r] = run2;
    run2 += blockCnt[(b0 + b) * NREL + r];
  }
}

// ---------------- Phase C: scatter (rel<<17 | sample) into sorted order ----------
__global__ __launch_bounds__(256) void phaseC_scatter(
    const int* __restrict__ rels, const int* __restrict__ blockOff,
    const int* __restrict__ binBase, int* __restrict__ permPacked) {
  __shared__ int cnt[NREL];
  __shared__ int baseArr[NREL];
  const int t = threadIdx.x;
  if (t < NREL) {
    cnt[t] = 0;
    baseArr[t] = binBase[t] + blockOff[blockIdx.x * NREL + t];
  }
  __syncthreads();
  const int s = blockIdx.x * SPB + t;
  const int rv = rels[s];
  const int rank = atomicAdd(&cnt[rv], 1);
  permPacked[baseArr[rv] + rank] = (rv << 17) | s;
}

// ---------------- Phase D: bilinear compute, one wave per 64 sorted samples ------
// Lane-per-sample; rows staged COALESCED into LDS (stride 65 = conflict-free for
// both the lane-column writes and the per-lane row reads, 2-way only == free).
__global__ __launch_bounds__(64) void bilinear_compute(
    const float* __restrict__ e1g, const float* __restrict__ e2g,
    const float* __restrict__ relE, const int* __restrict__ permPacked,
    float* __restrict__ out) {
  __shared__ float lds[DD * 65];  // 16.64 KB -> 8 blocks/CU fits in 160 KB
  const int lane = threadIdx.x;
  const int gid = blockIdx.x * 64 + lane;
  const int pk = permPacked[gid];
  const int b = pk & 0x1FFFF;
  int rr = pk >> 17;

  // Stage e2 rows of this wave's 64 samples: row i broadcast via readlane,
  // lane d reads element d -> one coalesced 256B load per row.
#pragma unroll 4
  for (int i = 0; i < DD; ++i) {
    const int pbi = __builtin_amdgcn_readlane(pk, i) & 0x1FFFF;
    lds[i * 65 + lane] = e2g[(size_t)pbi * DD + lane];
  }
  __syncthreads();
  // Transpose own e2 row into 64 VGPRs (2-way LDS aliasing only -> free).
  float e2[DD];
#pragma unroll
  for (int d = 0; d < DD; ++d) e2[d] = lds[lane * 65 + d];
  __syncthreads();
  // Reuse slab for e1 (stays in LDS; 1 ds_read per d-iteration in inner loop).
#pragma unroll 4
  for (int i = 0; i < DD; ++i) {
    const int pbi = __builtin_amdgcn_readlane(pk, i) & 0x1FFFF;
    lds[i * 65 + lane] = e1g[(size_t)pbi * DD + lane];
  }
  __syncthreads();

  const float* __restrict__ e1row = &lds[lane * 65];
  float score = 0.0f;
  // Waterfall: sorted order => at most 2 distinct rels per wave.
  for (;;) {
    const unsigned long long todo = __ballot(rr >= 0);
    if (todo == 0ull) break;
    const int leader = (int)__ffsll(todo) - 1;
    const int r0 = __builtin_amdgcn_readlane(rr, leader);  // SGPR
    if (rr == r0) {
      // r0 wave-uniform -> R streamed through s_load (SMEM pipe, free bcast)
      const float* __restrict__ R = relE + (size_t)r0 * (DD * DD);
      float sc = 0.0f;
      for (int d = 0; d < DD; ++d) {
        const float a = e1row[d];
        float t0 = 0.f, t1 = 0.f, t2 = 0.f, t3 = 0.f;
#pragma unroll
        for (int e = 0; e < DD; e += 4) {
          t0 = fmaf(R[d * DD + e + 0], e2[e + 0], t0);
          t1 = fmaf(R[d * DD + e + 1], e2[e + 1], t1);
          t2 = fmaf(R[d * DD + e + 2], e2[e + 2], t2);
          t3 = fmaf(R[d * DD + e + 3], e2[e + 3], t3);
        }
        sc = fmaf(a, (t0 + t1) + (t2 + t3), sc);
      }
      score = sc;
      rr = -1;
    }
  }
  out[b] = score;
}

extern "C" void kernel_launch(void* const* d_in, const int* in_sizes, int n_in,
                              void* d_out, int out_size, void* d_ws, size_t ws_size,
                              hipStream_t stream) {
  const float* e1 = (const float*)d_in[0];
  const float* e2 = (const float*)d_in[1];
  const int* rels = (const int*)d_in[2];
  const float* relE = (const float*)d_in[3];
  float* out = (float*)d_out;

  // Workspace (ints): permPacked[BB] | blockCnt[512*32] | blockOff[512*32] | binBase[32]
  int* permPacked = (int*)d_ws;
  int* blockCnt = permPacked + BB;
  int* blockOff = blockCnt + BLOCKS_AC * NREL;
  int* binBase = blockOff + BLOCKS_AC * NREL;

  phaseA_hist<<<BLOCKS_AC, 256, 0, stream>>>(rels, blockCnt);
  phaseB_scan<<<1, 256, 0, stream>>>(blockCnt, blockOff, binBase);
  phaseC_scatter<<<BLOCKS_AC, 256, 0, stream>>>(rels, blockOff, binBase, permPacked);
  bilinear_compute<<<BB / 64, 64, 0, stream>>>(e1, e2, relE, permPacked, out);
}

// Round 3
// 112.453 us; speedup vs baseline: 1.8251x; 1.7344x over previous
//
#include <hip/hip_runtime.h>
#include <hip/hip_bf16.h>
#include <cstddef>

// Problem constants
#define BB 131072
#define DD 64
#define NREL 32
#define PADN 133120            // BB + 2048 slack: bins padded to multiple of 64
#define NWAVE (PADN / 64)      // 2080 waves

// Sort phase decomposition
#define BLOCKS_AC 512
#define SPB (BB / BLOCKS_AC)   // 256 samples per block, 1 per thread
#define CHUNKS 8
#define BPC (BLOCKS_AC / CHUNKS)

typedef __attribute__((ext_vector_type(8))) __bf16 bf16x8;
typedef __attribute__((ext_vector_type(16))) float f32x16;

// ---------------- Phase A: per-block histogram + sentinel init of perm ----------
__global__ __launch_bounds__(256) void phaseA_hist(
    const int* __restrict__ rels, int* __restrict__ blockCnt,
    int* __restrict__ permPacked) {
  __shared__ int hist[NREL];
  const int t = threadIdx.x;
  if (t < NREL) hist[t] = 0;
  __syncthreads();
  const int gid = blockIdx.x * 256 + t;
  // sentinel-fill the padded perm buffer (overwritten by phaseC for real slots)
  permPacked[gid] = -1;
  if (gid < PADN - BB) permPacked[BB + gid] = -1;
  atomicAdd(&hist[rels[gid]], 1);
  __syncthreads();
  if (t < NREL) blockCnt[blockIdx.x * NREL + t] = hist[t];
}

// ---------------- Phase B: two-level scan; bin bases PADDED to multiple of 64 ---
__global__ __launch_bounds__(256) void phaseB_scan(
    const int* __restrict__ blockCnt, int* __restrict__ blockOff,
    int* __restrict__ binBase) {
  __shared__ int partial[CHUNKS][NREL];
  __shared__ int chunkBase[CHUNKS][NREL];
  __shared__ int binB[NREL];
  const int t = threadIdx.x;
  const int c = t >> 5;
  const int r = t & 31;
  const int b0 = c * BPC;
  int run = 0;
#pragma unroll 4
  for (int b = 0; b < BPC; ++b) run += blockCnt[(b0 + b) * NREL + r];
  partial[c][r] = run;
  __syncthreads();
  if (t < NREL) {
    int acc = 0;
#pragma unroll
    for (int i = 0; i < CHUNKS; ++i) { chunkBase[i][t] = acc; acc += partial[i][t]; }
  }
  __syncthreads();
  if (t == 0) {
    int acc = 0;
#pragma unroll
    for (int i = 0; i < NREL; ++i) {
      binB[i] = acc;
      const int tot = chunkBase[CHUNKS - 1][i] + partial[CHUNKS - 1][i];
      acc += (tot + 63) & ~63;   // pad each bin to full waves
    }
  }
  __syncthreads();
  if (t < NREL) binBase[t] = binB[t];
  int run2 = chunkBase[c][r];
#pragma unroll 4
  for (int b = 0; b < BPC; ++b) {
    blockOff[(b0 + b) * NREL + r] = run2;
    run2 += blockCnt[(b0 + b) * NREL + r];
  }
}

// ---------------- Phase C: scatter (rel<<17 | sample) into padded sorted order --
__global__ __launch_bounds__(256) void phaseC_scatter(
    const int* __restrict__ rels, const int* __restrict__ blockOff,
    const int* __restrict__ binBase, int* __restrict__ permPacked) {
  __shared__ int cnt[NREL];
  __shared__ int baseArr[NREL];
  const int t = threadIdx.x;
  if (t < NREL) {
    cnt[t] = 0;
    baseArr[t] = binBase[t] + blockOff[blockIdx.x * NREL + t];
  }
  __syncthreads();
  const int s = blockIdx.x * SPB + t;
  const int rv = rels[s];
  const int rank = atomicAdd(&cnt[rv], 1);
  permPacked[baseArr[rv] + rank] = (rv << 17) | s;
}

// ---------------- Phase D: MFMA bilinear, one wave per 64 rel-uniform samples ---
// P = E1 @ R via split-bf16 (hi+lo, 3 mfma products => ~fp32 precision), then
// score = rowsum(P .* E2) with E2 loaded directly in MFMA C-layout.
__global__ __launch_bounds__(64) void bilinear_mfma(
    const float* __restrict__ e1g, const float* __restrict__ e2g,
    const float* __restrict__ relE, const int* __restrict__ permPacked,
    float* __restrict__ out) {
  __shared__ float sA[DD * 65];  // E1 staging; reused as sP (stride 33) later
  const int lane = threadIdx.x;
  const int pk = permPacked[blockIdx.x * 64 + lane];
  const unsigned long long vm = __ballot(pk >= 0);
  if (vm == 0ull) return;  // fully-padded wave (uniform exit, before barriers)
  const int fv = (int)__builtin_ctzll(vm);
  const int r0 = __builtin_amdgcn_readlane(pk, fv) >> 17;  // bin => rel uniform
  const int h = lane >> 5;
  const int l31 = lane & 31;

  // Stage E1 rows coalesced: row i's sample broadcast via readlane, lane d
  // loads element d. Sentinel pk=-1 => b=0x1FFFF=131071 (valid addr, ignored).
#pragma unroll
  for (int i = 0; i < DD; ++i) {
    const int bi = __builtin_amdgcn_readlane(pk, i) & 0x1FFFF;
    sA[i * 65 + lane] = e1g[(size_t)bi * DD + lane];
  }
  __syncthreads();

  const float* __restrict__ R = relE + (size_t)r0 * (DD * DD);

  f32x16 acc[2][2];
#pragma unroll
  for (int ti = 0; ti < 2; ++ti)
#pragma unroll
    for (int tj = 0; tj < 2; ++tj)
#pragma unroll
      for (int i = 0; i < 16; ++i) acc[ti][tj][i] = 0.f;

#pragma unroll
  for (int kc = 0; kc < 4; ++kc) {
    // A-frags: A[m=32ti+l31][k=16kc+8h+j] from LDS (stride-65 => conflict-free)
    bf16x8 aH[2], aL[2], bH[2], bL[2];
#pragma unroll
    for (int ti = 0; ti < 2; ++ti) {
      const float* p = &sA[(32 * ti + l31) * 65 + kc * 16 + 8 * h];
#pragma unroll
      for (int j = 0; j < 8; ++j) {
        const float x = p[j];
        const __bf16 hb = (__bf16)x;
        const float lo = x - (float)hb;
        aH[ti][j] = hb;
        aL[ti][j] = (__bf16)lo;
      }
    }
    // B-frags: B[k=16kc+8h+j][n=32tj+l31] direct from R (rows 128B-coalesced)
#pragma unroll
    for (int tj = 0; tj < 2; ++tj) {
      const float* q = R + (size_t)(kc * 16 + 8 * h) * DD + 32 * tj + l31;
#pragma unroll
      for (int j = 0; j < 8; ++j) {
        const float x = q[(size_t)j * DD];
        const __bf16 hb = (__bf16)x;
        const float lo = x - (float)hb;
        bH[tj][j] = hb;
        bL[tj][j] = (__bf16)lo;
      }
    }
#pragma unroll
    for (int ti = 0; ti < 2; ++ti)
#pragma unroll
      for (int tj = 0; tj < 2; ++tj) {
        acc[ti][tj] = __builtin_amdgcn_mfma_f32_32x32x16_bf16(aH[ti], bH[tj], acc[ti][tj], 0, 0, 0);
        acc[ti][tj] = __builtin_amdgcn_mfma_f32_32x32x16_bf16(aH[ti], bL[tj], acc[ti][tj], 0, 0, 0);
        acc[ti][tj] = __builtin_amdgcn_mfma_f32_32x32x16_bf16(aL[ti], bH[tj], acc[ti][tj], 0, 0, 0);
      }
  }

  // Epilogue: C-layout row = 32ti + q + 8g + 4h, col = 32tj + l31.
  // E2 read directly in that layout (row uniform per half-wave => 128B segments).
  float rp[32];
#pragma unroll
  for (int i = 0; i < 32; ++i) rp[i] = 0.f;
#pragma unroll
  for (int ti = 0; ti < 2; ++ti)
#pragma unroll
    for (int g = 0; g < 4; ++g)
#pragma unroll
      for (int q = 0; q < 4; ++q) {
        const int reg = g * 4 + q;  // row_in_tile = (reg&3) + 8*(reg>>2) + 4h
        const int rbase = 32 * ti + q + 8 * g;
        const int s0 = __builtin_amdgcn_readlane(pk, rbase) & 0x1FFFF;
        const int s1 = __builtin_amdgcn_readlane(pk, rbase + 4) & 0x1FFFF;
        const int bs = h ? s1 : s0;
        const float* er = e2g + (size_t)bs * DD + l31;
        rp[ti * 16 + reg] = fmaf(acc[ti][0][reg], er[0],
                            fmaf(acc[ti][1][reg], er[32], rp[ti * 16 + reg]));
      }

  // Cross-lane reduce over l31 via LDS transpose (stride 33 => conflict-free)
  __syncthreads();
  float* sP = sA;
#pragma unroll
  for (int ti = 0; ti < 2; ++ti)
#pragma unroll
    for (int g = 0; g < 4; ++g)
#pragma unroll
      for (int q = 0; q < 4; ++q) {
        const int row = 32 * ti + q + 8 * g + 4 * h;
        sP[row * 33 + l31] = rp[ti * 16 + g * 4 + q];
      }
  __syncthreads();
  float sc = 0.f;
#pragma unroll
  for (int c = 0; c < 32; ++c) sc += sP[lane * 33 + c];
  if (pk >= 0) out[pk & 0x1FFFF] = sc;
}

extern "C" void kernel_launch(void* const* d_in, const int* in_sizes, int n_in,
                              void* d_out, int out_size, void* d_ws, size_t ws_size,
                              hipStream_t stream) {
  const float* e1 = (const float*)d_in[0];
  const float* e2 = (const float*)d_in[1];
  const int* rels = (const int*)d_in[2];
  const float* relE = (const float*)d_in[3];
  float* out = (float*)d_out;

  // Workspace (ints): permPacked[PADN] | blockCnt[512*32] | blockOff[512*32] | binBase[32]
  int* permPacked = (int*)d_ws;
  int* blockCnt = permPacked + PADN;
  int* blockOff = blockCnt + BLOCKS_AC * NREL;
  int* binBase = blockOff + BLOCKS_AC * NREL;

  phaseA_hist<<<BLOCKS_AC, 256, 0, stream>>>(rels, blockCnt, permPacked);
  phaseB_scan<<<1, 256, 0, stream>>>(blockCnt, blockOff, binBase);
  phaseC_scatter<<<BLOCKS_AC, 256, 0, stream>>>(rels, blockOff, binBase, permPacked);
  bilinear_mfma<<<NWAVE, 64, 0, stream>>>(e1, e2, relE, permPacked, out);
}